// Round 4
// baseline (139.716 us; speedup 1.0000x reference)
//
#include <hip/hip_runtime.h>
#include <hip/hip_bf16.h>
#include <math.h>

// Problem constants (fixed by setup_inputs)
#define NB      2      // batch
#define T_IN    12
#define T_OUT_  24
#define O_OUT   12     // T_OUT - T_IN
#define NN      10000  // nodes
#define CC      16     // channels
#define KK      17     // neighbors
#define HH      4      // heads
#define JJ      48     // T_IN * HH
#define NPC     80     // nodes per chunk
#define NCHUNK  125    // 125 * 80 = 10000
#define PPG     3      // planes per group (24 planes / 8 XCD groups)
#define NPS     4      // nodes per shrink block

// ---- bf16 helpers (RNE pack, shift unpack) ----
__device__ __forceinline__ unsigned short f2bf(float f) {
    union { float f; unsigned int u; } v; v.f = f;
    unsigned int r = v.u + 0x7FFFu + ((v.u >> 16) & 1u);
    return (unsigned short)(r >> 16);
}
__device__ __forceinline__ float bf2f(unsigned int lo16) {
    union { unsigned int u; float f; } v; v.u = lo16 << 16;
    return v.f;
}

// ---------------- sigma = max(nearest_dists), single block ----------------
// Single workgroup -> no atomic, no zero-init, no memset dispatch.
__global__ __launch_bounds__(1024) void sigma_single_kernel(
    const float* __restrict__ d, int n, unsigned int* __restrict__ out) {
    float m = 0.0f;  // dists are uniform [0,1): non-negative
    const int nv4 = n >> 2;
    const float4* d4 = (const float4*)d;
    for (int i = threadIdx.x; i < nv4; i += 1024) {
        float4 v = d4[i];
        m = fmaxf(fmaxf(m, fmaxf(v.x, v.y)), fmaxf(v.z, v.w));
    }
    for (int i = (nv4 << 2) + threadIdx.x; i < n; i += 1024) m = fmaxf(m, d[i]);
    #pragma unroll
    for (int off = 32; off > 0; off >>= 1)
        m = fmaxf(m, __shfl_down(m, off, 64));
    __shared__ float sm[16];
    int lane = threadIdx.x & 63, wid = threadIdx.x >> 6;
    if (lane == 0) sm[wid] = m;
    __syncthreads();
    if (threadIdx.x == 0) {
        float mm = sm[0];
        #pragma unroll
        for (int w = 1; w < 16; ++w) mm = fmaxf(mm, sm[w]);
        *out = __float_as_uint(mm);
    }
}

// ---------------- phase 1: fused weights + gather + aggregate ---------------
// grid = 8 groups x 125 chunks = 1000 blocks. group g handles planes
// {g, g+8, g+16} (all == g mod 8 -> same XCD under blockIdx%8 heuristic), so
// each XCD's L2 holds 3 planes (1.9 MB) for the entire kernel.
// Weights computed during LDS staging (f32; 1 expf + 3 muls per record).
// agg layout: (n, b, t, c, h) bf16 -> one uint2 store per (thread, plane).
__global__ __launch_bounds__(256) void aggregate_kernel(
    const float* __restrict__ x,
    const int*   __restrict__ nodes,
    const float* __restrict__ dists,
    const unsigned int* __restrict__ sigma_bits,
    float* __restrict__ out,
    unsigned short* __restrict__ agg)
{
    const int g     = blockIdx.x & 7;
    const int chunk = blockIdx.x >> 3;       // 0..124
    const int n0    = chunk * NPC;
    const int tid   = threadIdx.x;

    __shared__ int   lds_idx[NPC * KK];      // 5.4 KB  (byte offsets)
    __shared__ float lds_w[NPC * KK][HH];    // 21.8 KB (f32 weights)

    // ---- stage records: compute weights on the fly ----
    const float sigma  = __uint_as_float(*sigma_bits);
    const float inv_s2 = 1.0f / (sigma * sigma);
    const int rbase = n0 * KK;
    for (int j = tid; j < NPC * KK; j += 256) {
        const int   nd = nodes[rbase + j];
        const float dd = dists[rbase + j];
        const float q  = dd * dd * inv_s2;
        const float e1 = expf(-q * 0.25f);   // w_h = e1^(h+1)
        float w0 = e1, w1 = e1 * e1, w2 = w1 * e1, w3 = w1 * w1;
        if (nd == -1) { w0 = w1 = w2 = w3 = 0.f; }
        if (w0 < 1e-8f) w0 = 0.f;
        if (w1 < 1e-8f) w1 = 0.f;
        if (w2 < 1e-8f) w2 = 0.f;
        if (w3 < 1e-8f) w3 = 0.f;
        lds_idx[j]   = ((nd < 0) ? 0 : nd) * (CC * 4);
        lds_w[j][0] = w0; lds_w[j][1] = w1; lds_w[j][2] = w2; lds_w[j][3] = w3;
    }
    __syncthreads();

    // plane set for this group
    int plane[PPG], bb[PPG], tt[PPG];
    const char* xb[PPG];
    #pragma unroll
    for (int p = 0; p < PPG; ++p) {
        plane[p] = g + 8 * p;                // 0..23
        bb[p] = plane[p] / T_IN;
        tt[p] = plane[p] % T_IN;
        xb[p] = (const char*)(x + (long)plane[p] * NN * CC);
    }

    const int c  = tid & 15;
    const int nl = tid >> 4;                 // 0..15
    const int cb = c * 4;                    // byte offset of channel

    for (int it = 0; it < NPC / 16; ++it) {
        const int n_local = nl + 16 * it;    // 0..79
        const int n  = n0 + n_local;
        const int rb = n_local * KK;

        float a0[PPG], a1[PPG], a2[PPG], a3[PPG];
        #pragma unroll
        for (int p = 0; p < PPG; ++p) { a0[p]=0.f; a1[p]=0.f; a2[p]=0.f; a3[p]=0.f; }

        #pragma unroll
        for (int k = 0; k < KK; ++k) {
            const int   off = lds_idx[rb + k] + cb;
            const float w0 = lds_w[rb + k][0];
            const float w1 = lds_w[rb + k][1];
            const float w2 = lds_w[rb + k][2];
            const float w3 = lds_w[rb + k][3];
            float gv[PPG];
            #pragma unroll
            for (int p = 0; p < PPG; ++p)
                gv[p] = *(const float*)(xb[p] + off);
            #pragma unroll
            for (int p = 0; p < PPG; ++p) {
                a0[p] += gv[p] * w0;
                a1[p] += gv[p] * w1;
                a2[p] += gv[p] * w2;
                a3[p] += gv[p] * w3;
            }
        }

        #pragma unroll
        for (int p = 0; p < PPG; ++p) {
            uint2 pk;
            pk.x = (unsigned)f2bf(a0[p]) | ((unsigned)f2bf(a1[p]) << 16);
            pk.y = (unsigned)f2bf(a2[p]) | ((unsigned)f2bf(a3[p]) << 16);
            // agg (n,b,t,c,h): uint2 index = ((n*NB+b)*T_IN+t)*CC + c
            ((uint2*)agg)[(((n * NB + bb[p]) * T_IN + tt[p]) * CC) + c] = pk;
        }
    }

    // ---- passthrough for the 3 planes: out[b,t,chunk] = x[b,t,chunk] ----
    #pragma unroll
    for (int p = 0; p < PPG; ++p) {
        const float4* src = (const float4*)(x + (long)plane[p] * NN * CC + n0 * CC);
        float4* dst = (float4*)(out + (long)(bb[p] * T_OUT_ + tt[p]) * NN * CC + n0 * CC);
        for (int i = tid; i < NPC * CC / 4; i += 256)   // 320 float4
            dst[i] = src[i];
    }
}

// ---------------- phase 2: 48-term shrink matmul + SELU ----------------
// 4 nodes per block; agg read directly from global (coalesced 128B rows,
// o-lanes broadcast); only W/bias staged in LDS.
__global__ __launch_bounds__(384) void shrink_kernel(
    const unsigned short* __restrict__ agg,
    const float* __restrict__ Wm, const float* __restrict__ bias,
    float* __restrict__ out)
{
    const int tid = threadIdx.x;

    __shared__ float W_s[O_OUT * JJ];   // 2.25 KB
    __shared__ float b_s[O_OUT];

    for (int i = tid; i < O_OUT * JJ; i += 384) W_s[i] = Wm[i];
    if (tid < O_OUT) b_s[tid] = bias[tid];
    __syncthreads();

    const int c    = tid & 15;
    const int rest = tid >> 4;      // 0..23
    const int o    = rest % O_OUT;
    const int b    = rest / O_OUT;

    const float kScale = 1.0507009873554805f;
    const float kAlpha = 1.6732632423543772f;

    #pragma unroll
    for (int u = 0; u < NPS; ++u) {
        const int n = blockIdx.x * NPS + u;
        // agg (n,b,t,c,h): uint2 index = ((n*NB+b)*T_IN+t)*CC + c
        const uint2* ap = (const uint2*)agg + ((long)(n * NB + b) * T_IN) * CC + c;

        float y = b_s[o];
        #pragma unroll
        for (int t = 0; t < T_IN; ++t) {
            const uint2 v = ap[t * CC];
            const int wb = o * JJ + t * HH;
            y += bf2f(v.x & 0xffffu) * W_s[wb + 0];
            y += bf2f(v.x >> 16)     * W_s[wb + 1];
            y += bf2f(v.y & 0xffffu) * W_s[wb + 2];
            y += bf2f(v.y >> 16)     * W_s[wb + 3];
        }

        y = (y > 0.0f) ? kScale * y : kScale * kAlpha * expm1f(y);
        out[((long)(b * T_OUT_ + T_IN + o) * NN + n) * CC + c] = y;
    }
}

extern "C" void kernel_launch(void* const* d_in, const int* in_sizes, int n_in,
                              void* d_out, int out_size, void* d_ws, size_t ws_size,
                              hipStream_t stream) {
    const float* x     = (const float*)d_in[0];
    const int*   nodes = (const int*)  d_in[1];
    const float* dists = (const float*)d_in[2];
    const float* Wm    = (const float*)d_in[3];
    const float* bias  = (const float*)d_in[4];
    float* out = (float*)d_out;

    // ws layout: [0,4)=sigma | 256: agg (N*B*T*C*H bf16, 30.72 MB)
    char* ws = (char*)d_ws;
    unsigned int*   sigma_bits = (unsigned int*)ws;
    unsigned short* agg        = (unsigned short*)(ws + 256);

    const int nd = in_sizes[2];  // N*K = 170000
    sigma_single_kernel<<<1, 1024, 0, stream>>>(dists, nd, sigma_bits);
    aggregate_kernel<<<8 * NCHUNK, 256, 0, stream>>>(x, nodes, dists,
                                                     sigma_bits, out, agg);
    shrink_kernel<<<NN / NPS, 384, 0, stream>>>(agg, Wm, bias, out);
}